// Round 4
// baseline (2390.323 us; speedup 1.0000x reference)
//
#include <hip/hip_runtime.h>

// QuestionFlowLayer: out[i] = concat(q[i], mean(q[0:i])) for q [1024, 64, 1024] f32.
//
// Minimal-traffic block-scan, round 3: no full vmcnt drains.
//  - Block = 256 threads (4 waves) owns 64 consecutive scalar columns; wave w
//    handles a 32-row chunk per 128-row super-step (8 super-steps).
//  - Cross-wave prefix exchange through 2 KB LDS with RAW s_barrier +
//    lgkmcnt(0) only (NOT __syncthreads, which drains vmcnt(0) and killed R2).
//  - Global loads double-buffered in registers: super-step s+1's rows are
//    prefetched before step s is summed/emitted. Explicit 2-step loop body
//    (ping-pong) so all register indices are compile-time constants.
//  - Input read once (268 MB), output written once (537 MB).
constexpr int N_TURNS = 1024;
constexpr int D_MOD   = 1024;
constexpr unsigned COLS    = 65536;                  // L*D scalar columns
constexpr unsigned OUT_ROW = 2u * 64 * D_MOD;        // floats per turn in out

constexpr int WAVES = 4;
constexpr int RPW   = 32;                            // rows per wave per step
constexpr int ROWS_PER_STEP = WAVES * RPW;           // 128
constexpr int NSTEP = N_TURNS / ROWS_PER_STEP;       // 8 (even)

__global__ __launch_bounds__(256, 4) void qflow_scan_dbuf(
        const float* __restrict__ q, float* __restrict__ out) {
    __shared__ float csum[2][WAVES][64];             // ping-pong exchange buf

    const unsigned lane = threadIdx.x & 63u;
    const unsigned w    = threadIdx.x >> 6;
    const unsigned c    = blockIdx.x * 64u + lane;   // scalar column
    const unsigned l    = c >> 10;
    const unsigned d    = c & (D_MOD - 1u);

    const float* qp = q + c;                         // q[i][c] = qp[i*COLS]
    // +2048B bias: v at imm -2048, avg at imm +2048 from one address.
    float* opb = out + (size_t)l * (2u * D_MOD) + d + 512u;

    float vA[RPW], vB[RPW];
    float superPrefix = 0.0f;

    auto prefetch = [&](float (&v)[RPW], unsigned s) {
        const unsigned base = s * ROWS_PER_STEP + w * RPW;
        #pragma unroll
        for (int j = 0; j < RPW; ++j)
            v[j] = qp[(size_t)(base + j) * COLS];
    };

    auto process = [&](float (&v)[RPW], unsigned s, unsigned pb) {
        // chunk sum (waits only on this buffer's loads)
        float chunk = 0.0f;
        #pragma unroll
        for (int j = 0; j < RPW; ++j) chunk += v[j];

        csum[pb][w][lane] = chunk;
        asm volatile("s_waitcnt lgkmcnt(0)" ::: "memory");
        __builtin_amdgcn_s_barrier();                // LDS-only rendezvous

        float run = superPrefix;
        float total = 0.0f;
        #pragma unroll
        for (int w2 = 0; w2 < WAVES; ++w2) {
            float t = csum[pb][w2][lane];
            if ((unsigned)w2 < w) run += t;
            total += t;
        }

        const unsigned base = s * ROWS_PER_STEP + w * RPW;
        #pragma unroll
        for (int j = 0; j < RPW; ++j) {
            const unsigned i = base + j;
            const float inv = (i == 0) ? 0.0f : __builtin_amdgcn_rcpf((float)i);
            const float avg = run * inv;
            const size_t ob = (size_t)i * OUT_ROW;
            opb[ob - 512] = v[j];                    // out[i][l][d]
            opb[ob + 512] = avg;                     // out[i][l][D+d]
            run += v[j];
        }
        superPrefix += total;
    };

    prefetch(vA, 0);
    for (unsigned s = 0; s < (unsigned)NSTEP; s += 2) {
        prefetch(vB, s + 1);                         // s+1 <= NSTEP-1 always
        process(vA, s, 0);
        if (s + 2 < (unsigned)NSTEP) prefetch(vA, s + 2);
        process(vB, s + 1, 1);
    }
}

extern "C" void kernel_launch(void* const* d_in, const int* in_sizes, int n_in,
                              void* d_out, int out_size, void* d_ws, size_t ws_size,
                              hipStream_t stream) {
    const float* q = (const float*)d_in[0];
    float* out = (float*)d_out;
    qflow_scan_dbuf<<<COLS / 64, 256, 0, stream>>>(q, out);
}

// Round 5
// 168.065 us; speedup vs baseline: 14.2226x; 14.2226x over previous
//
#include <hip/hip_runtime.h>

// QuestionFlowLayer: out[i] = concat(q[i], mean(q[0:i])) for q [1024, 64, 1024] f32.
//
// Minimal-traffic block-scan, round 4 (spill-proofed R3):
//  - Block = 512 threads (8 waves) owns 64 consecutive scalar columns; wave w
//    handles a 16-row chunk per 128-row super-step (8 super-steps).
//  - Straight-line code, ONE v[16] array per thread (no lambdas, no ping-pong
//    register arrays -- R3's version spilled: VGPR=64 with 64-float arrays,
//    FETCH 2.77 GB of scratch traffic).
//  - Cross-wave prefix via 4 KB ping-pong LDS; raw s_barrier + lgkmcnt(0)
//    only (no vmcnt drain -- __syncthreads killed R2).
//  - Input read once (268 MB), output written once (537 MB).
constexpr int N_TURNS = 1024;
constexpr int D_MOD   = 1024;
constexpr unsigned COLS    = 65536;               // L*D scalar columns
constexpr unsigned OUT_ROW = 2u * 64 * D_MOD;     // floats per turn in out

constexpr int WAVES = 8;
constexpr int RPW   = 16;                         // rows per wave per step
constexpr int ROWS_PER_STEP = WAVES * RPW;        // 128
constexpr int NSTEP = N_TURNS / ROWS_PER_STEP;    // 8

__global__ __launch_bounds__(512) void qflow_scan_r4(
        const float* __restrict__ q, float* __restrict__ out) {
    __shared__ float csum[2][WAVES][64];          // ping-pong exchange buffer

    const unsigned lane = threadIdx.x & 63u;
    const unsigned w    = threadIdx.x >> 6;       // wave id [0,8)
    const unsigned c    = blockIdx.x * 64u + lane;
    const unsigned l    = c >> 10;
    const unsigned d    = c & (D_MOD - 1u);

    const float* qp = q + c;                      // q[i][c] = qp[i*COLS]
    // +2048B bias: v at imm -2048, avg at imm +2048 from one address.
    float* opb = out + (size_t)l * (2u * D_MOD) + d + 512u;

    float superPrefix = 0.0f;

    for (unsigned s = 0; s < (unsigned)NSTEP; ++s) {
        const unsigned base = s * ROWS_PER_STEP + w * RPW;
        const unsigned pb = s & 1u;

        float v[RPW];
        #pragma unroll
        for (int j = 0; j < RPW; ++j)
            v[j] = qp[(size_t)(base + j) * COLS];

        float chunk = 0.0f;
        #pragma unroll
        for (int j = 0; j < RPW; ++j) chunk += v[j];

        csum[pb][w][lane] = chunk;
        asm volatile("s_waitcnt lgkmcnt(0)" ::: "memory");
        __builtin_amdgcn_s_barrier();             // LDS-only rendezvous
        __builtin_amdgcn_sched_barrier(0);        // pin DS reads below barrier

        float run = superPrefix;
        float total = 0.0f;
        #pragma unroll
        for (int w2 = 0; w2 < WAVES; ++w2) {
            float t = csum[pb][w2][lane];
            total += t;
            if ((unsigned)w2 < w) run += t;
        }

        #pragma unroll
        for (int j = 0; j < RPW; ++j) {
            const unsigned i = base + j;
            const float inv = (i == 0) ? 0.0f : __builtin_amdgcn_rcpf((float)i);
            const float avg = run * inv;
            const size_t ob = (size_t)i * OUT_ROW;
            opb[ob - 512] = v[j];                 // out[i][l][d]
            opb[ob + 512] = avg;                  // out[i][l][D+d]
            run += v[j];
        }
        superPrefix += total;
    }
}

extern "C" void kernel_launch(void* const* d_in, const int* in_sizes, int n_in,
                              void* d_out, int out_size, void* d_ws, size_t ws_size,
                              hipStream_t stream) {
    const float* q = (const float*)d_in[0];
    float* out = (float*)d_out;
    qflow_scan_r4<<<COLS / 64, 512, 0, stream>>>(q, out);
}